// Round 5
// baseline (445.127 us; speedup 1.0000x reference)
//
#include <hip/hip_runtime.h>
#include <stdint.h>

#define N_SPK 2048
#define M_UTT 16
#define D_EMB 512
#define NM (N_SPK * M_UTT)
#define FP8_SCALE 16.0f   // quantization scale for fp8 operands (1/256 folded into w)

typedef __attribute__((ext_vector_type(4))) float f32x4;
typedef __attribute__((ext_vector_type(4))) int   i32x4;
typedef __attribute__((ext_vector_type(8))) int   i32x8;

__device__ __forceinline__ void async_copy16(const void* g, void* l) {
    __builtin_amdgcn_global_load_lds(
        (const __attribute__((address_space(1))) unsigned int*)g,
        (__attribute__((address_space(3))) unsigned int*)l,
        16, 0, 0);
}

// read one 32B (K=128) MFMA fragment from swizzled LDS: global granule 2q at
// slot s0 = 2q ^ (row&7), granule 2q+1 at s0^1.
__device__ __forceinline__ i32x8 ld_frag(const unsigned char* base, int s0) {
    i32x4 lo = *(const i32x4*)(base + s0 * 16);
    i32x4 hi = *(const i32x4*)(base + (s0 ^ 1) * 16);
    return __builtin_shufflevector(lo, hi, 0, 1, 2, 3, 4, 5, 6, 7);
}

// ---------------------------------------------------------------------------
// Kernel A: per-speaker prep (unchanged from round 4 except cnt zeroing).
// 256 thr/block, thread t owns dims {2t, 2t+1}. Single global pass; outputs
// fp8 e4m3 at x16 scale. dterm fp32-exact. Folds colsum/cnt/out zeroing.
// ---------------------------------------------------------------------------
__global__ __launch_bounds__(256) void prep_kernel(
    const float* __restrict__ V, const float* __restrict__ wp,
    const float* __restrict__ bp, unsigned char* __restrict__ Cn8,
    unsigned char* __restrict__ vn8, float* __restrict__ dterm,
    float* __restrict__ colsum, int* __restrict__ cnt, float* __restrict__ out)
{
    const int spk = blockIdx.x, t = threadIdx.x;
    const int wave = t >> 6, lane = t & 63;
    const float2* vb = (const float2*)(V + (size_t)spk * (M_UTT * D_EMB)); // [16][256]

    __shared__ __align__(16) float red[32][264];  // rows 0..15 sv, 16..31 vv (+8 pad)
    __shared__ float red2[32];
    __shared__ float invs[M_UTT];
    __shared__ float wred[4];

    // folded zeroing of colsum + cnt + out
    if (spk < 128) colsum[spk * 256 + t] = 0.f;
    if (spk == 128) cnt[t] = 0;
    if (spk == 0 && t == 0) out[0] = 0.f;

    // ---- single global read pass ----
    float2 p[M_UTT];
#pragma unroll
    for (int m = 0; m < M_UTT; ++m) p[m] = vb[m * 256 + t];

    float2 ss = make_float2(0.f, 0.f);
#pragma unroll
    for (int m = 0; m < M_UTT; ++m) { ss.x += p[m].x; ss.y += p[m].y; }

    // ||ssum||^2 butterfly (4 waves -> wred)
    float cnp = ss.x * ss.x + ss.y * ss.y;
#pragma unroll
    for (int off = 32; off > 0; off >>= 1) cnp += __shfl_xor(cnp, off);
    if (lane == 0) wred[wave] = cnp;

    // per-utterance partials -> LDS
#pragma unroll
    for (int m = 0; m < M_UTT; ++m) {
        red[m][t]         = ss.x * p[m].x + ss.y * p[m].y;          // <ssum, v> part
        red[m + M_UTT][t] = p[m].x * p[m].x + p[m].y * p[m].y;      // ||v||^2 part
    }
    __syncthreads();
    const float cn2 = wred[0] + wred[1] + wred[2] + wred[3];

    // ---- batched row reduction: 8 threads per row, 8 float4 each ----
    {
        const int r = t >> 3, s = t & 7;
        const float4* rp = (const float4*)red;   // row stride = 66 float4
        float4 a = make_float4(0.f, 0.f, 0.f, 0.f);
#pragma unroll
        for (int k = 0; k < 8; ++k) {
            float4 q = rp[r * 66 + s + 8 * k];
            a.x += q.x; a.y += q.y; a.z += q.z; a.w += q.w;
        }
        float v1 = (a.x + a.y) + (a.z + a.w);
        v1 += __shfl_xor(v1, 1);
        v1 += __shfl_xor(v1, 2);
        v1 += __shfl_xor(v1, 4);
        if (s == 0) red2[r] = v1;
    }
    __syncthreads();

    // ---- per-utterance scalars (fp32-exact leave-one-out sims) ----
    if (t < M_UTT) {
        const float sv = red2[t], vv = red2[t + M_UTT];
        const float cc = cn2 - 2.f * sv + vv;      // ||ssum - v||^2
        const float cv = sv - vv;                  // <ssum - v, v>
        const float dc = fmaxf(sqrtf(fmaxf(cc, 0.f)) * (1.f / (M_UTT - 1)), 1e-8f) * (M_UTT - 1);
        const float dv = fmaxf(sqrtf(vv), 1e-8f);
        dterm[spk * M_UTT + t] = (*wp) * (cv / (dc * dv)) + (*bp);
        invs[t] = FP8_SCALE / dv;
    }
    __syncthreads();

    // ---- fp8 outputs (x16 scale) ----
    const float cs = FP8_SCALE / (M_UTT * fmaxf(sqrtf(cn2) * (1.f / M_UTT), 1e-8f));
    {
        int pk = __builtin_amdgcn_cvt_pk_fp8_f32(ss.x * cs, ss.y * cs, 0, false);
        ((unsigned short*)(Cn8 + (size_t)spk * D_EMB))[t] = (unsigned short)pk;
    }
#pragma unroll
    for (int m = 0; m < M_UTT; ++m) {
        const float iv = invs[m];
        int pk = __builtin_amdgcn_cvt_pk_fp8_f32(p[m].x * iv, p[m].y * iv, 0, false);
        ((unsigned short*)(vn8 + ((size_t)(spk * M_UTT + m)) * D_EMB))[t] = (unsigned short)pk;
    }
}

// ---------------------------------------------------------------------------
// Kernel B: MX-scaled fp8 GEMM (mfma_scale_f32_16x16x128_f8f6f4, scales=1.0)
// fused with exp(w'S+b), same-speaker masking, column reduction, AND the
// final logsumexp/loss (last block per bx via atomic counter).
// 128x128 tile, BK=128, 4 waves of 64x64 = 4x4 K=128 MFMA tiles.
// LDS swizzle: 16B slot s of row r holds global granule s ^ (r&7); staging
// lane lambda loads global granule (lambda&7)^((lambda>>3)&7). Fragment b128
// reads give a per-8-lane bank-group permutation (corrected sub-group rule).
// ---------------------------------------------------------------------------
__global__ __launch_bounds__(256) void gemm_kernel(
    const unsigned char* __restrict__ Cn8, const unsigned char* __restrict__ vn8,
    const float* __restrict__ wp, const float* __restrict__ bp,
    float* __restrict__ colsum, const float* __restrict__ dterm,
    int* __restrict__ cnt, float* __restrict__ out)
{
    __shared__ __align__(16) unsigned char As[128 * 128];
    __shared__ __align__(16) unsigned char Bs[128 * 128];
    __shared__ float csum[128];
    __shared__ float fin[2];
    __shared__ int lastf;

    const int tid = threadIdx.x;
    const int w = tid >> 6, l = tid & 63;
    const int by = blockIdx.x;   // speaker tiles   [0,16)  (fast-varying)
    const int bx = blockIdx.y;   // utterance tiles [0,256)
    const float wgt = (*wp) * (1.f / (FP8_SCALE * FP8_SCALE));
    const float bsc = *bp;

    if (tid < 128) csum[tid] = 0.f;

    // staging: wave w covers rows w*32..+32, 4 issues x 8 rows x 16B/lane.
    const int srow = w * 32 + (l >> 3);
    const int sg   = (l & 7) ^ ((l >> 3) & 7);
    const unsigned char* Ab = Cn8 + (size_t)(by * 128 + srow) * D_EMB + sg * 16;
    const unsigned char* Bb = vn8 + (size_t)(bx * 128 + srow) * D_EMB + sg * 16;
    unsigned char* AsW = As + (w * 32) * 128;
    unsigned char* BsW = Bs + (w * 32) * 128;

    // compute geometry: 2x2 wave grid, each wave 64x64 = 4x4 MFMA (K=128)
    const int wm = w & 1, wn = w >> 1;
    const int l16 = l & 15, q = l >> 4;
    const int s0 = ((l >> 3) & 6) ^ (l & 7);   // = 2q ^ (row&7), row&7 == l&7
    const unsigned char* Ard = As + (wm * 64 + l16) * 128;
    const unsigned char* Brd = Bs + (wn * 64 + l16) * 128;

    f32x4 acc[4][4];
    const f32x4 z = {0.f, 0.f, 0.f, 0.f};
#pragma unroll
    for (int i = 0; i < 4; ++i)
#pragma unroll
        for (int j = 0; j < 4; ++j) acc[i][j] = z;

    for (int kk = 0; kk < D_EMB; kk += 128) {
        __syncthreads();
#pragma unroll
        for (int i = 0; i < 4; ++i) {
            async_copy16(Ab + kk + (size_t)(i * 8) * D_EMB, AsW + i * 1024);
            async_copy16(Bb + kk + (size_t)(i * 8) * D_EMB, BsW + i * 1024);
        }
        __syncthreads();
        i32x8 bfr[4];
#pragma unroll
        for (int j = 0; j < 4; ++j) bfr[j] = ld_frag(Brd + j * 2048, s0);
#pragma unroll
        for (int i = 0; i < 4; ++i) {
            i32x8 af = ld_frag(Ard + i * 2048, s0);
#pragma unroll
            for (int j = 0; j < 4; ++j)
                acc[i][j] = __builtin_amdgcn_mfma_scale_f32_16x16x128_f8f6f4(
                    af, bfr[j], acc[i][j], 0, 0, 0, 0x7F7F7F7F, 0, 0x7F7F7F7F);
        }
    }

    // epilogue: e = exp(w'*dot+b), zero same-speaker entries, reduce over rows.
    // C/D layout (shape-determined): row = q*4 + r, col = l16.
    const int rowg0 = by * 128 + wm * 64 + q * 4;
    const int colg0 = bx * 128 + wn * 64 + l16;
#pragma unroll
    for (int j = 0; j < 4; ++j) {
        const int colg = colg0 + j * 16;
        const int cspk = colg >> 4;       // speaker owning this column
        float p = 0.f;
#pragma unroll
        for (int i = 0; i < 4; ++i) {
            const int rowg = rowg0 + i * 16;
#pragma unroll
            for (int r = 0; r < 4; ++r) {
                float e = __expf(wgt * acc[i][j][r] + bsc);
                p += (rowg + r == cspk) ? 0.f : e;
            }
        }
        p += __shfl_xor(p, 16);
        p += __shfl_xor(p, 32);
        if (q == 0) atomicAdd(&csum[wn * 64 + j * 16 + l16], p);
    }
    __syncthreads();
    if (tid < 128) atomicAdd(&colsum[bx * 128 + tid], csum[tid]);
    __syncthreads();

    // ---- fused finish: last block for this bx computes the 128 losses ----
    if (tid == 0) {
        __threadfence();
        lastf = (atomicAdd(&cnt[bx], 1) == (int)gridDim.x - 1);
    }
    __syncthreads();
    if (lastf) {
        __threadfence();
        float loc = 0.f;
        if (tid < 128) {
            const int jj = bx * 128 + tid;
            const float csv = atomicAdd(&colsum[jj], 0.0f);  // coherent read
            const float dt  = dterm[jj];
            loc = logf(csv + __expf(dt)) - dt;
        }
#pragma unroll
        for (int off = 32; off > 0; off >>= 1) loc += __shfl_xor(loc, off);
        if (l == 0 && w < 2) fin[w] = loc;
        __syncthreads();
        if (tid == 0) atomicAdd(out, fin[0] + fin[1]);
    }
}

extern "C" void kernel_launch(void* const* d_in, const int* in_sizes, int n_in,
                              void* d_out, int out_size, void* d_ws, size_t ws_size,
                              hipStream_t stream) {
    const float* V  = (const float*)d_in[0];
    const float* wp = (const float*)d_in[1];
    const float* bp = (const float*)d_in[2];

    char* ws = (char*)d_ws;
    unsigned char* Cn8 = (unsigned char*)ws;                        //  1 MB [2048][512] fp8
    unsigned char* vn8 = (unsigned char*)(ws + ((size_t)1 << 20));  // 16 MB [32768][512] fp8
    float* dterm  = (float*)(ws + ((size_t)17 << 20));              // 128 KB
    float* colsum = dterm + NM;                                     // 128 KB
    int*   cnt    = (int*)(colsum + NM);                            // 1 KB [256]
    float* out    = (float*)d_out;

    prep_kernel<<<N_SPK, 256, 0, stream>>>(V, wp, bp, Cn8, vn8, dterm, colsum, cnt, out);
    gemm_kernel<<<dim3(N_SPK / 128, NM / 128), 256, 0, stream>>>(
        Cn8, vn8, wp, bp, colsum, dterm, cnt, out);
}

// Round 6
// 149.218 us; speedup vs baseline: 2.9831x; 2.9831x over previous
//
#include <hip/hip_runtime.h>
#include <stdint.h>

#define N_SPK 2048
#define M_UTT 16
#define D_EMB 512
#define NM (N_SPK * M_UTT)
#define FP8_SCALE 16.0f   // quantization scale for fp8 operands (1/256 folded into w)

typedef __attribute__((ext_vector_type(4))) float f32x4;
typedef __attribute__((ext_vector_type(4))) int   i32x4;
typedef __attribute__((ext_vector_type(8))) int   i32x8;

__device__ __forceinline__ void async_copy16(const void* g, void* l) {
    __builtin_amdgcn_global_load_lds(
        (const __attribute__((address_space(1))) unsigned int*)g,
        (__attribute__((address_space(3))) unsigned int*)l,
        16, 0, 0);
}

// read one 32B (K=128) MFMA fragment from swizzled LDS: global granule 2q at
// slot s0 = 2q ^ (row&7), granule 2q+1 at s0^1. base includes the 128B-half.
__device__ __forceinline__ i32x8 ld_frag(const unsigned char* base, int s0) {
    i32x4 lo = *(const i32x4*)(base + s0 * 16);
    i32x4 hi = *(const i32x4*)(base + (s0 ^ 1) * 16);
    return __builtin_shufflevector(lo, hi, 0, 1, 2, 3, 4, 5, 6, 7);
}

// ---------------------------------------------------------------------------
// Kernel A: per-speaker prep. 256 thr/block, thread t owns dims {2t, 2t+1}.
// Single global pass; outputs fp8 e4m3 at x16 scale. dterm fp32-exact.
// Folds colsum/out zeroing.
// ---------------------------------------------------------------------------
__global__ __launch_bounds__(256) void prep_kernel(
    const float* __restrict__ V, const float* __restrict__ wp,
    const float* __restrict__ bp, unsigned char* __restrict__ Cn8,
    unsigned char* __restrict__ vn8, float* __restrict__ dterm,
    float* __restrict__ colsum, float* __restrict__ out)
{
    const int spk = blockIdx.x, t = threadIdx.x;
    const int wave = t >> 6, lane = t & 63;
    const float2* vb = (const float2*)(V + (size_t)spk * (M_UTT * D_EMB)); // [16][256]

    __shared__ __align__(16) float red[32][264];  // rows 0..15 sv, 16..31 vv (+8 pad)
    __shared__ float red2[32];
    __shared__ float invs[M_UTT];
    __shared__ float wred[4];

    // folded zeroing of colsum + out
    if (spk < 128) colsum[spk * 256 + t] = 0.f;
    if (spk == 0 && t == 0) out[0] = 0.f;

    // ---- single global read pass ----
    float2 p[M_UTT];
#pragma unroll
    for (int m = 0; m < M_UTT; ++m) p[m] = vb[m * 256 + t];

    float2 ss = make_float2(0.f, 0.f);
#pragma unroll
    for (int m = 0; m < M_UTT; ++m) { ss.x += p[m].x; ss.y += p[m].y; }

    // ||ssum||^2 butterfly (4 waves -> wred)
    float cnp = ss.x * ss.x + ss.y * ss.y;
#pragma unroll
    for (int off = 32; off > 0; off >>= 1) cnp += __shfl_xor(cnp, off);
    if (lane == 0) wred[wave] = cnp;

    // per-utterance partials -> LDS
#pragma unroll
    for (int m = 0; m < M_UTT; ++m) {
        red[m][t]         = ss.x * p[m].x + ss.y * p[m].y;          // <ssum, v> part
        red[m + M_UTT][t] = p[m].x * p[m].x + p[m].y * p[m].y;      // ||v||^2 part
    }
    __syncthreads();
    const float cn2 = wred[0] + wred[1] + wred[2] + wred[3];

    // ---- batched row reduction: 8 threads per row, 8 float4 each ----
    {
        const int r = t >> 3, s = t & 7;
        const float4* rp = (const float4*)red;   // row stride = 66 float4
        float4 a = make_float4(0.f, 0.f, 0.f, 0.f);
#pragma unroll
        for (int k = 0; k < 8; ++k) {
            float4 q = rp[r * 66 + s + 8 * k];
            a.x += q.x; a.y += q.y; a.z += q.z; a.w += q.w;
        }
        float v1 = (a.x + a.y) + (a.z + a.w);
        v1 += __shfl_xor(v1, 1);
        v1 += __shfl_xor(v1, 2);
        v1 += __shfl_xor(v1, 4);
        if (s == 0) red2[r] = v1;
    }
    __syncthreads();

    // ---- per-utterance scalars (fp32-exact leave-one-out sims) ----
    if (t < M_UTT) {
        const float sv = red2[t], vv = red2[t + M_UTT];
        const float cc = cn2 - 2.f * sv + vv;      // ||ssum - v||^2
        const float cv = sv - vv;                  // <ssum - v, v>
        const float dc = fmaxf(sqrtf(fmaxf(cc, 0.f)) * (1.f / (M_UTT - 1)), 1e-8f) * (M_UTT - 1);
        const float dv = fmaxf(sqrtf(vv), 1e-8f);
        dterm[spk * M_UTT + t] = (*wp) * (cv / (dc * dv)) + (*bp);
        invs[t] = FP8_SCALE / dv;
    }
    __syncthreads();

    // ---- fp8 outputs (x16 scale) ----
    const float cs = FP8_SCALE / (M_UTT * fmaxf(sqrtf(cn2) * (1.f / M_UTT), 1e-8f));
    {
        int pk = __builtin_amdgcn_cvt_pk_fp8_f32(ss.x * cs, ss.y * cs, 0, false);
        ((unsigned short*)(Cn8 + (size_t)spk * D_EMB))[t] = (unsigned short)pk;
    }
#pragma unroll
    for (int m = 0; m < M_UTT; ++m) {
        const float iv = invs[m];
        int pk = __builtin_amdgcn_cvt_pk_fp8_f32(p[m].x * iv, p[m].y * iv, 0, false);
        ((unsigned short*)(vn8 + ((size_t)(spk * M_UTT + m)) * D_EMB))[t] = (unsigned short)pk;
    }
}

// ---------------------------------------------------------------------------
// Kernel B: MX-scaled fp8 GEMM (mfma_scale_f32_16x16x128_f8f6f4, scales=1.0)
// fused with exp(w'S+b), same-speaker masking, column reduction.
// 128x128 tile, BK=256 (2 K-iterations, 32 MFMAs per barrier pair),
// 4 waves of 64x64. NO device fences (round-5 lesson: __threadfence = L2
// writeback-inv, ~310us over the grid).
// LDS: 256B rows = 2 x 128B halves; granule g of row r at slot g^(r&7)
// within its half. Staging lane L: row += L>>4, half = (L>>3)&1, slot = L&7;
// source granule = slot ^ (row&7) (even/odd issue pointers differ in bit 2).
// Fragment b128 reads hit distinct bank-quads per 8-lane group.
// ---------------------------------------------------------------------------
__global__ __launch_bounds__(256) void gemm_kernel(
    const unsigned char* __restrict__ Cn8, const unsigned char* __restrict__ vn8,
    const float* __restrict__ wp, const float* __restrict__ bp,
    float* __restrict__ colsum)
{
    __shared__ __align__(16) unsigned char As[128 * 256];
    __shared__ __align__(16) unsigned char Bs[128 * 256];
    __shared__ float csum[128];

    const int tid = threadIdx.x;
    const int w = tid >> 6, l = tid & 63;
    const int by = blockIdx.x;   // speaker tiles   [0,16)  (fast-varying)
    const int bx = blockIdx.y;   // utterance tiles [0,256)
    const float wgt = (*wp) * (1.f / (FP8_SCALE * FP8_SCALE));
    const float bsc = *bp;

    if (tid < 128) csum[tid] = 0.f;

    // staging geometry: wave w covers rows w*32..w*32+31; 8 issues per matrix
    // per kk, each issue = 4 rows x 256B. Lane L: r_l = L>>4, h = (L>>3)&1,
    // s = L&7. Even issues: srow&7 = r_l; odd: r_l^4.
    const int r_l = l >> 4, hh = (l >> 3) & 1, sl8 = l & 7;
    const int g_even = sl8 ^ r_l;
    const size_t rowoff = (size_t)(w * 32 + r_l) * D_EMB + hh * 128;
    const unsigned char* Ab0 = Cn8 + (size_t)(by * 128) * D_EMB + rowoff + g_even * 16;
    const unsigned char* Ab1 = Cn8 + (size_t)(by * 128) * D_EMB + rowoff + (g_even ^ 4) * 16;
    const unsigned char* Bb0 = vn8 + (size_t)(bx * 128) * D_EMB + rowoff + g_even * 16;
    const unsigned char* Bb1 = vn8 + (size_t)(bx * 128) * D_EMB + rowoff + (g_even ^ 4) * 16;
    unsigned char* AsW = As + (w * 32) * 256;
    unsigned char* BsW = Bs + (w * 32) * 256;

    // compute geometry: 2x2 wave grid, each wave 64x64 = 4x4 MFMA (K=128)
    const int wm = w & 1, wn = w >> 1;
    const int l16 = l & 15, q = l >> 4;
    const int s0 = (2 * q) ^ (l & 7);
    const unsigned char* Ard = As + (wm * 64 + l16) * 256;
    const unsigned char* Brd = Bs + (wn * 64 + l16) * 256;

    f32x4 acc[4][4];
    const f32x4 z = {0.f, 0.f, 0.f, 0.f};
#pragma unroll
    for (int i = 0; i < 4; ++i)
#pragma unroll
        for (int j = 0; j < 4; ++j) acc[i][j] = z;

#pragma unroll
    for (int kk = 0; kk < D_EMB; kk += 256) {
        __syncthreads();
#pragma unroll
        for (int i = 0; i < 8; ++i) {
            const unsigned char* pa = ((i & 1) ? Ab1 : Ab0) + i * 2048 + kk;
            const unsigned char* pb = ((i & 1) ? Bb1 : Bb0) + i * 2048 + kk;
            async_copy16(pa, AsW + i * 1024);
            async_copy16(pb, BsW + i * 1024);
        }
        __syncthreads();
#pragma unroll
        for (int h2 = 0; h2 < 2; ++h2) {
            const int ho = h2 * 128;
            i32x8 bfr[4];
#pragma unroll
            for (int j = 0; j < 4; ++j) bfr[j] = ld_frag(Brd + j * 4096 + ho, s0);
#pragma unroll
            for (int i = 0; i < 4; ++i) {
                i32x8 af = ld_frag(Ard + i * 4096 + ho, s0);
#pragma unroll
                for (int j = 0; j < 4; ++j)
                    acc[i][j] = __builtin_amdgcn_mfma_scale_f32_16x16x128_f8f6f4(
                        af, bfr[j], acc[i][j], 0, 0, 0, 0x7F7F7F7F, 0, 0x7F7F7F7F);
            }
        }
    }

    // epilogue: e = exp(w'*dot+b), zero same-speaker entries, reduce over rows.
    // C/D layout (shape-determined): row = q*4 + r, col = l16.
    const int rowg0 = by * 128 + wm * 64 + q * 4;
    const int colg0 = bx * 128 + wn * 64 + l16;
#pragma unroll
    for (int j = 0; j < 4; ++j) {
        const int colg = colg0 + j * 16;
        const int cspk = colg >> 4;       // speaker owning this column
        float p = 0.f;
#pragma unroll
        for (int i = 0; i < 4; ++i) {
            const int rowg = rowg0 + i * 16;
#pragma unroll
            for (int r = 0; r < 4; ++r) {
                float e = __expf(wgt * acc[i][j][r] + bsc);
                p += (rowg + r == cspk) ? 0.f : e;
            }
        }
        p += __shfl_xor(p, 16);
        p += __shfl_xor(p, 32);
        if (q == 0) atomicAdd(&csum[wn * 64 + j * 16 + l16], p);
    }
    __syncthreads();
    if (tid < 128) atomicAdd(&colsum[bx * 128 + tid], csum[tid]);
}

// ---------------------------------------------------------------------------
// Kernel C: L_j = -dterm_j + log(colsum_j + exp(dterm_j)); sum -> out[0]
// ---------------------------------------------------------------------------
__global__ __launch_bounds__(256) void finish_kernel(
    const float* __restrict__ dterm, const float* __restrict__ colsum,
    float* __restrict__ out)
{
    const int idx = blockIdx.x * 256 + threadIdx.x;
    const int stride = gridDim.x * 256;
    float local = 0.f;
    for (int j = idx; j < NM; j += stride) {
        float t = dterm[j];
        local += logf(colsum[j] + __expf(t)) - t;
    }
#pragma unroll
    for (int off = 32; off > 0; off >>= 1) local += __shfl_xor(local, off);
    __shared__ float wr[4];
    const int wave = threadIdx.x >> 6, lane = threadIdx.x & 63;
    if (lane == 0) wr[wave] = local;
    __syncthreads();
    if (threadIdx.x == 0) atomicAdd(out, wr[0] + wr[1] + wr[2] + wr[3]);
}

extern "C" void kernel_launch(void* const* d_in, const int* in_sizes, int n_in,
                              void* d_out, int out_size, void* d_ws, size_t ws_size,
                              hipStream_t stream) {
    const float* V  = (const float*)d_in[0];
    const float* wp = (const float*)d_in[1];
    const float* bp = (const float*)d_in[2];

    char* ws = (char*)d_ws;
    unsigned char* Cn8 = (unsigned char*)ws;                        //  1 MB [2048][512] fp8
    unsigned char* vn8 = (unsigned char*)(ws + ((size_t)1 << 20));  // 16 MB [32768][512] fp8
    float* dterm  = (float*)(ws + ((size_t)17 << 20));              // 128 KB
    float* colsum = dterm + NM;                                     // 128 KB
    float* out    = (float*)d_out;

    prep_kernel<<<N_SPK, 256, 0, stream>>>(V, wp, bp, Cn8, vn8, dterm, colsum, out);
    gemm_kernel<<<dim3(N_SPK / 128, NM / 128), 256, 0, stream>>>(Cn8, vn8, wp, bp, colsum);
    finish_kernel<<<64, 256, 0, stream>>>(dterm, colsum, out);
}